// Round 3
// baseline (1079.261 us; speedup 1.0000x reference)
//
#include <hip/hip_runtime.h>

// SemanticCaps dynamic routing, fp32. B=128, J=10, K=1152, M=16, I=8.
// R3: u_hat is NEVER materialized. u = Ws@x is recomputed from LDS-staged Ws
// (16 FLOP/elem beats 4 B/elem of LLC traffic — R2 showed uhat/iter kernels
// were Infinity-Cache-BW bound at ~7.9 TB/s on 755 MB of Ws/u_hat re-reads).
// b-logit algebra: b after t iters = u.(v0+...+v_{t-1}), so only running v-sum
// is needed, no b tensor.
//
// ws layout (floats): s0[20480] s1[20480] s2[20480] v0[20480] vsum[20480]

#define B_ 128
#define J_ 10
#define K_ 1152
#define M_ 16
#define KT 8             // k per block
#define BT 64            // b per block
#define NKT (K_ / KT)    // 144
#define NBT (B_ / BT)    // 2
#define PSTR 321         // kl row stride in float4 (10*32 + 1) -> 1284 floats
                         // 1284 % 32 == 4 -> 8 kl rows hit disjoint bank quads

// dot8: u[m] contribution from one (k,m) row of Ws and x[b,k,:]
__device__ __forceinline__ float dot8(float4 w0, float4 w1, float4 x0, float4 x1) {
    return w0.x * x0.x + w0.y * x0.y + w0.z * x0.z + w0.w * x0.w
         + w1.x * x1.x + w1.y * x1.y + w1.z * x1.z + w1.w * x1.w;
}

// MODE 0: s_out += sum_k u        (iteration 0, c uniform; 0.1 applied in squash)
// MODE 1: s_out += sum_k c*u with c = softmax_j(u . vin)
template <int MODE>
__global__ __launch_bounds__(512, 4)
void iter_kernel(const float* __restrict__ x, const float* __restrict__ Ws,
                 const float* __restrict__ vin, float* __restrict__ s_out) {
    __shared__ float4 ws4[KT * PSTR];   // ~41 KB: Ws[k0..k0+7][all j][16m][8i]

    const int t  = threadIdx.x;
    const int k0 = blockIdx.x * KT;
    const int b  = blockIdx.y * BT + (t >> 3);
    const int kl = t & (KT - 1);
    const int k  = k0 + kl;

    // ---- stage Ws slice (all j) into LDS: 2560 float4, coalesced ----
    const float4* wsg = (const float4*)Ws;
    for (int l = t; l < KT * J_ * 32; l += 512) {
        const int j = l >> 8, r = l & 255, klw = r >> 5, c = r & 31;
        ws4[klw * PSTR + j * 32 + c] = wsg[((size_t)j * K_ + k0 + klw) * 32 + c];
    }

    const float4* xv = (const float4*)(x + ((size_t)b * K_ + k) * 8);
    const float4 x0 = xv[0], x1 = xv[1];
    __syncthreads();

    float e[J_];
    float inv = 1.f;

    if (MODE == 1) {
        // ---- pass 1: logits -> exp -> denominator ----
        float den = 0.f;
#pragma unroll
        for (int j = 0; j < J_; ++j) {
            const float4* wr = ws4 + kl * PSTR + j * 32;
            float u[M_];
#pragma unroll
            for (int m = 0; m < M_; ++m) u[m] = dot8(wr[2 * m], wr[2 * m + 1], x0, x1);
            const float4* vb = (const float4*)(vin + ((size_t)b * J_ + j) * M_);
            const float4 va = vb[0], vq = vb[1], vc = vb[2], vd = vb[3];
            const float lg = u[0] * va.x + u[1] * va.y + u[2] * va.z + u[3] * va.w
                           + u[4] * vq.x + u[5] * vq.y + u[6] * vq.z + u[7] * vq.w
                           + u[8] * vc.x + u[9] * vc.y + u[10] * vc.z + u[11] * vc.w
                           + u[12] * vd.x + u[13] * vd.y + u[14] * vd.z + u[15] * vd.w;
            e[j] = __expf(lg);
            den += e[j];
        }
        inv = 1.f / den;
    }

    // ---- pass 2 (or only pass): weighted accumulation into s_out ----
#pragma unroll
    for (int j = 0; j < J_; ++j) {
        const float4* wr = ws4 + kl * PSTR + j * 32;
        float u[M_];
#pragma unroll
        for (int m = 0; m < M_; ++m) u[m] = dot8(wr[2 * m], wr[2 * m + 1], x0, x1);
        const float c = (MODE == 1) ? e[j] * inv : 1.0f;
#pragma unroll
        for (int m = 0; m < M_; ++m) {
            float r = c * u[m];
            r += __shfl_xor(r, 1, 64);
            r += __shfl_xor(r, 2, 64);
            r += __shfl_xor(r, 4, 64);
            u[m] = r;
        }
        if (kl == 0) {
            float* dst = s_out + ((size_t)b * J_ + j) * M_;
#pragma unroll
            for (int m = 0; m < M_; ++m) atomicAdd(dst + m, u[m]);
        }
    }
}

// SM 0: vout = squash(0.1*s)   SM 1: vout = v0 + squash(s)   SM 2: vout = squash(s)
template <int SM>
__global__ __launch_bounds__(256)
void squash_kernel(const float* __restrict__ sin, const float* __restrict__ v0,
                   float* __restrict__ vout) {
    const int g = blockIdx.x * 256 + threadIdx.x;   // 20480 = B*J*M
    float s = sin[g];
    if (SM == 0) s *= 0.1f;
    float sq = s * s;
    sq += __shfl_xor(sq, 1, 64);
    sq += __shfl_xor(sq, 2, 64);
    sq += __shfl_xor(sq, 4, 64);
    sq += __shfl_xor(sq, 8, 64);
    const float n = sqrtf(sq);
    float v = s * (n / (1.f + sq));
    if (SM == 1) v += v0[g];
    vout[g] = v;
}

extern "C" void kernel_launch(void* const* d_in, const int* in_sizes, int n_in,
                              void* d_out, int out_size, void* d_ws, size_t ws_size,
                              hipStream_t stream) {
    const float* x  = (const float*)d_in[0];   // [128][1152][8]
    const float* Ws = (const float*)d_in[1];   // [10][1152][16][8]
    float* out = (float*)d_out;                // [128][10][16]

    const size_t NV = (size_t)B_ * J_ * M_;    // 20480
    float* s0   = (float*)d_ws;
    float* s1   = s0 + NV;
    float* s2   = s1 + NV;
    float* v0   = s2 + NV;
    float* vsum = v0 + NV;

    hipMemsetAsync(s0, 0, 3 * NV * sizeof(float), stream);   // zero s0,s1,s2

    dim3 gi(NKT, NBT);
    iter_kernel<0><<<gi, 512, 0, stream>>>(x, Ws, nullptr, s0);
    squash_kernel<0><<<80, 256, 0, stream>>>(s0, nullptr, v0);
    iter_kernel<1><<<gi, 512, 0, stream>>>(x, Ws, v0, s1);
    squash_kernel<1><<<80, 256, 0, stream>>>(s1, v0, vsum);
    iter_kernel<1><<<gi, 512, 0, stream>>>(x, Ws, vsum, s2);
    squash_kernel<2><<<80, 256, 0, stream>>>(s2, nullptr, out);
}

// Round 4
// 204.919 us; speedup vs baseline: 5.2668x; 5.2668x over previous
//
#include <hip/hip_runtime.h>

// SemanticCaps dynamic routing, fp32. B=128, J=10, K=1152, M=16, I=8.
// R4: full recompute (u_hat never materialized), ZERO atomics (R3's killer:
// 2.95M fabric atomics = 92MB WRITE_SIZE, 3.3/cyc throughput-bound).
// Blocks write disjoint per-k-tile partials; squash kernels fold them.
// b-logit algebra: b after t iters = u.(v0+..+v_{t-1}) (b starts at 0).
//
// Lane layout (64): kl = lane>>3 (k within 8-tile), mq = (lane>>1)&3 (m-quad),
// bl = lane&1. Block 256 thr = 4 waves; wave w covers b-subset; each thread
// serially covers 4 b's. Block b-coverage 32, grid (144 k-tiles, 4 b-groups).
//
// ws layout (floats): sp[2,949,120] c[1,474,560] v0[20480] vsum[20480]

#define B_ 128
#define J_ 10
#define K_ 1152
#define M_ 16
#define KT 8               // k per block tile
#define NTILE (K_ / KT)    // 144
#define WSTR 361           // ws4 kl-row stride in float4 (10*36+1)
#define JSTR 36            // ws4 j stride in float4 (4*9)
#define QSTR 9             // ws4 mq stride in float4 (8+1 pad)

__device__ __forceinline__ float dot8(float4 w0, float4 w1, float4 xa, float4 xb) {
    return w0.x * xa.x + w0.y * xa.y + w0.z * xa.z + w0.w * xa.w
         + w1.x * xb.x + w1.y * xb.y + w1.z * xb.z + w1.w * xb.w;
}

// stage Ws[all j][k0..k0+7][16m][8i] into padded LDS (46.2 KB)
__device__ __forceinline__ void stage_ws(float4* ws4, const float4* wsg, int k0, int t) {
    for (int l = t; l < KT * J_ * 32; l += 256) {
        const int j = l >> 8, rem = l & 255;
        const int kl = rem >> 5, c = rem & 31;
        const int mq = c >> 3, r = c & 7;
        ws4[kl * WSTR + j * JSTR + mq * QSTR + r] =
            wsg[((size_t)j * K_ + k0 + kl) * 32 + c];
    }
}

// ---------------- logit kernel: c[b][j][k] = softmax_j( u . vin ) ----------
__global__ __launch_bounds__(256)
void logit_kernel(const float* __restrict__ x, const float* __restrict__ Ws,
                  const float* __restrict__ vin, float* __restrict__ c_out) {
    __shared__ float4 ws4[KT * WSTR];
    const int t = threadIdx.x, w = t >> 6, lane = t & 63;
    const int kl = lane >> 3, mq = (lane >> 1) & 3, bl = lane & 1;
    const int k0 = blockIdx.x * KT, k = k0 + kl;
    const int bb = blockIdx.y * 32 + w * 8 + bl;   // + bs*2

    stage_ws(ws4, (const float4*)Ws, k0, t);

    float4 xr[4][2];
#pragma unroll
    for (int bs = 0; bs < 4; ++bs) {
        const float4* xg = (const float4*)(x + ((size_t)(bb + bs * 2) * K_ + k) * 8);
        xr[bs][0] = xg[0]; xr[bs][1] = xg[1];
    }
    __syncthreads();

    float den[4] = {0.f, 0.f, 0.f, 0.f};
    float e[J_][4];
#pragma unroll
    for (int j = 0; j < J_; ++j) {
        const float4* wr = ws4 + kl * WSTR + j * JSTR + mq * QSTR;
        const float4 w0 = wr[0], w1 = wr[1], w2 = wr[2], w3 = wr[3];
        const float4 w4 = wr[4], w5 = wr[5], w6 = wr[6], w7 = wr[7];
#pragma unroll
        for (int bs = 0; bs < 4; ++bs) {
            const int b = bb + bs * 2;
            const float4 xa = xr[bs][0], xb = xr[bs][1];
            const float u0 = dot8(w0, w1, xa, xb), u1 = dot8(w2, w3, xa, xb);
            const float u2 = dot8(w4, w5, xa, xb), u3 = dot8(w6, w7, xa, xb);
            const float4 v4 = *(const float4*)(vin + ((size_t)b * J_ + j) * M_ + mq * 4);
            float p = u0 * v4.x + u1 * v4.y + u2 * v4.z + u3 * v4.w;
            p += __shfl_xor(p, 2, 64);     // reduce over mq (lane bits 1,2)
            p += __shfl_xor(p, 4, 64);
            e[j][bs] = __expf(p);
            den[bs] += e[j][bs];
        }
    }
    float inv[4];
#pragma unroll
    for (int bs = 0; bs < 4; ++bs) inv[bs] = 1.f / den[bs];

    // each mq lane writes j = mq, mq+4, mq+8 (compile-time j, predicated)
#pragma unroll
    for (int j = 0; j < J_; ++j) {
        if ((j & 3) == mq) {
#pragma unroll
            for (int bs = 0; bs < 4; ++bs) {
                const int b = bb + bs * 2;
                c_out[((size_t)b * J_ + j) * K_ + k] = e[j][bs] * inv[bs];
            }
        }
    }
}

// ---------------- accum kernel: sp[b][j][tile][m] = sum_{k in tile} c*u ----
// MODE 0: c == 1 (iteration 0; the 1/10 is folded into squash<0>)
template <int MODE>
__global__ __launch_bounds__(256)
void accum_kernel(const float* __restrict__ x, const float* __restrict__ Ws,
                  const float* __restrict__ c_in, float* __restrict__ sp) {
    __shared__ float4 ws4[KT * WSTR];
    const int t = threadIdx.x, w = t >> 6, lane = t & 63;
    const int kl = lane >> 3, mq = (lane >> 1) & 3, bl = lane & 1;
    const int k0 = blockIdx.x * KT, k = k0 + kl;
    const int tile = blockIdx.x;
    const int bb = blockIdx.y * 32 + w * 8 + bl;

    stage_ws(ws4, (const float4*)Ws, k0, t);

    float4 xr[4][2];
#pragma unroll
    for (int bs = 0; bs < 4; ++bs) {
        const float4* xg = (const float4*)(x + ((size_t)(bb + bs * 2) * K_ + k) * 8);
        xr[bs][0] = xg[0]; xr[bs][1] = xg[1];
    }
    __syncthreads();

#pragma unroll
    for (int j = 0; j < J_; ++j) {
        const float4* wr = ws4 + kl * WSTR + j * JSTR + mq * QSTR;
        const float4 w0 = wr[0], w1 = wr[1], w2 = wr[2], w3 = wr[3];
        const float4 w4 = wr[4], w5 = wr[5], w6 = wr[6], w7 = wr[7];
#pragma unroll
        for (int bs = 0; bs < 4; ++bs) {
            const int b = bb + bs * 2;
            const float4 xa = xr[bs][0], xb = xr[bs][1];
            const float cc = (MODE == 1) ? c_in[((size_t)b * J_ + j) * K_ + k] : 1.0f;
            float r0 = cc * dot8(w0, w1, xa, xb);
            float r1 = cc * dot8(w2, w3, xa, xb);
            float r2 = cc * dot8(w4, w5, xa, xb);
            float r3 = cc * dot8(w6, w7, xa, xb);
            // reduce over kl (lane bits 3,4,5)
#pragma unroll
            for (int d = 8; d <= 32; d <<= 1) {
                r0 += __shfl_xor(r0, d, 64);
                r1 += __shfl_xor(r1, d, 64);
                r2 += __shfl_xor(r2, d, 64);
                r3 += __shfl_xor(r3, d, 64);
            }
            if (kl == 0) {
                float4 o; o.x = r0; o.y = r1; o.z = r2; o.w = r3;
                *(float4*)(sp + (((size_t)b * J_ + j) * NTILE + tile) * M_ + mq * 4) = o;
            }
        }
    }
}

// ------------- squash: fold 144 tile-partials, squash, emit v --------------
// SM 0: v0 = squash(0.1*S)   SM 1: vsum = v0 + squash(S)   SM 2: out = squash(S)
template <int SM>
__global__ __launch_bounds__(256)
void squash_kernel(const float* __restrict__ sp, const float* __restrict__ v0,
                   float* __restrict__ vout) {
    const int g = blockIdx.x * 256 + threadIdx.x;   // 20480 = B*J*M
    const int m = g & 15, bj = g >> 4;
    float s = 0.f;
    for (int tt = 0; tt < NTILE; ++tt) s += sp[(size_t)bj * (NTILE * M_) + tt * M_ + m];
    if (SM == 0) s *= 0.1f;
    float sq = s * s;
    sq += __shfl_xor(sq, 1, 64);
    sq += __shfl_xor(sq, 2, 64);
    sq += __shfl_xor(sq, 4, 64);
    sq += __shfl_xor(sq, 8, 64);
    const float n = sqrtf(sq);
    float v = s * (n / (1.f + sq));
    if (SM == 1) v += v0[g];
    vout[g] = v;
}

extern "C" void kernel_launch(void* const* d_in, const int* in_sizes, int n_in,
                              void* d_out, int out_size, void* d_ws, size_t ws_size,
                              hipStream_t stream) {
    const float* x  = (const float*)d_in[0];   // [128][1152][8]
    const float* Ws = (const float*)d_in[1];   // [10][1152][16][8]
    float* out = (float*)d_out;                // [128][10][16]

    float* sp   = (float*)d_ws;                                   // 2,949,120
    float* cbuf = sp + (size_t)B_ * J_ * NTILE * M_;              // 1,474,560
    float* v0   = cbuf + (size_t)B_ * J_ * K_;                    //    20,480
    float* vsum = v0 + B_ * J_ * M_;                              //    20,480

    const dim3 g(NTILE, 4);

    // iter 0: c uniform -> sp -> v0
    accum_kernel<0><<<g, 256, 0, stream>>>(x, Ws, nullptr, sp);
    squash_kernel<0><<<80, 256, 0, stream>>>(sp, nullptr, v0);
    // iter 1
    logit_kernel<<<g, 256, 0, stream>>>(x, Ws, v0, cbuf);
    accum_kernel<1><<<g, 256, 0, stream>>>(x, Ws, cbuf, sp);
    squash_kernel<1><<<80, 256, 0, stream>>>(sp, v0, vsum);
    // iter 2
    logit_kernel<<<g, 256, 0, stream>>>(x, Ws, vsum, cbuf);
    accum_kernel<1><<<g, 256, 0, stream>>>(x, Ws, cbuf, sp);
    squash_kernel<2><<<80, 256, 0, stream>>>(sp, nullptr, out);
}

// Round 5
// 145.774 us; speedup vs baseline: 7.4037x; 1.4057x over previous
//
#include <hip/hip_runtime.h>

// SemanticCaps dynamic routing, fp32. B=128, J=10, K=1152, M=16, I=8.
// R5: b-minor layouts everywhere (lane = batch), wave = output-capsule j,
// u[16] kept in registers between logit and accumulation (no recompute, no
// c tensor), Ws read via the SCALAR path (wave-uniform address after
// readfirstlane(j) -> s_load + FMA with SGPR operand).
// b-logit algebra: b after t iters = u.(v0+..+v_{t-1}) (b starts at 0).
//
// ws (floats): xT[9216*128] sp[128*10*128*16] v0T[20480] vsumT[20480]

#define B_ 128
#define J_ 10
#define K_ 1152
#define M_ 16
#define I_ 8
#define KT 9
#define NKT (K_ / KT)     // 128 k-tiles
#define RW (K_ * I_)      // 9216 rows of xT

// ---------- transpose x[b][k][i] -> xT[k*8+i][b] (LDS-tiled, coalesced) ----
__global__ __launch_bounds__(256)
void xpose_kernel(const float* __restrict__ x, float* __restrict__ xT) {
    __shared__ float tile[64 * 65];
    const int t = threadIdx.x;
    const int r0 = blockIdx.x * 64, b0 = blockIdx.y * 64;
    const int hi = t >> 6, lo = t & 63;
#pragma unroll 4
    for (int c = 0; c < 16; ++c) {
        const int bb = c * 4 + hi;
        tile[lo * 65 + bb] = x[(size_t)(b0 + bb) * RW + r0 + lo];
    }
    __syncthreads();
#pragma unroll 4
    for (int c = 0; c < 16; ++c) {
        const int r = c * 4 + hi;
        xT[(size_t)(r0 + r) * B_ + b0 + lo] = tile[r * 65 + lo];
    }
}

// ---------- routing iteration ------------------------------------------------
// MODE 0: c == 1 (iteration 0; 0.1 folded into squash<0>)
// MODE 1: c = softmax_j(u . vin);  s = sum_k c*u  (u stays in registers)
template <int MODE>
__global__ __launch_bounds__(640)
void iter_kernel(const float* __restrict__ xT, const float* __restrict__ Ws,
                 const float* __restrict__ vinT, float* __restrict__ sp) {
    __shared__ float earr[2][J_ * 64];
    const int t  = threadIdx.x;
    const int bl = t & 63;
    const int j  = __builtin_amdgcn_readfirstlane(t >> 6);  // wave-uniform j
    const int kt = blockIdx.x, bg = blockIdx.y;
    const int b  = bg * 64 + bl;

    float v[M_], s[M_];
#pragma unroll
    for (int m = 0; m < M_; ++m) s[m] = 0.f;
    if (MODE == 1) {
        const float4* vp = (const float4*)(vinT + ((size_t)j * B_ + b) * M_);
#pragma unroll
        for (int q = 0; q < 4; ++q) {
            const float4 w = vp[q];
            v[q * 4] = w.x; v[q * 4 + 1] = w.y; v[q * 4 + 2] = w.z; v[q * 4 + 3] = w.w;
        }
    }

    for (int kk = 0; kk < KT; ++kk) {
        const int k = kt * KT + kk;
        float xr[I_];
#pragma unroll
        for (int i = 0; i < I_; ++i) xr[i] = xT[(size_t)(k * I_ + i) * B_ + b];

        const float* w = Ws + ((size_t)j * K_ + k) * (M_ * I_);  // uniform -> s_load
        float u[M_];
#pragma unroll
        for (int m = 0; m < M_; ++m) {
            float a = 0.f;
#pragma unroll
            for (int i = 0; i < I_; ++i) a += w[m * I_ + i] * xr[i];
            u[m] = a;
        }

        if (MODE == 1) {
            float lg = 0.f;
#pragma unroll
            for (int m = 0; m < M_; ++m) lg += u[m] * v[m];
            const float e = __expf(lg);
            earr[kk & 1][j * 64 + bl] = e;
            __syncthreads();   // one barrier/k; ping-pong makes reuse race-free
            float den = 0.f;
#pragma unroll
            for (int jj = 0; jj < J_; ++jj) den += earr[kk & 1][jj * 64 + bl];
            const float c = __fdividef(e, den);
#pragma unroll
            for (int m = 0; m < M_; ++m) s[m] += c * u[m];
        } else {
#pragma unroll
            for (int m = 0; m < M_; ++m) s[m] += u[m];
        }
    }

    float4* o = (float4*)(sp + (((size_t)kt * J_ + j) * B_ + b) * M_);
#pragma unroll
    for (int q = 0; q < 4; ++q) {
        float4 w;
        w.x = s[q * 4]; w.y = s[q * 4 + 1]; w.z = s[q * 4 + 2]; w.w = s[q * 4 + 3];
        o[q] = w;
    }
}

// ---------- squash: fold 128 coalesced tile-partials, emit v -----------------
// SM 0: v0T = squash(0.1*S)  SM 1: vsumT = v0T + squash(S)  SM 2: out = squash(S)
template <int SM>
__global__ __launch_bounds__(256)
void squash_kernel(const float* __restrict__ sp, const float* __restrict__ v0T,
                   float* __restrict__ dst) {
    const int g = blockIdx.x * 256 + threadIdx.x;   // g = (j*128+b)*16+m
    const int m = g & 15;
    const int b = (g >> 4) & 127;
    const int j = g >> 11;
    float S = 0.f;
#pragma unroll 8
    for (int tt = 0; tt < NKT; ++tt)
        S += sp[(((size_t)tt * J_ + j) * B_ + b) * M_ + m];
    if (SM == 0) S *= 0.1f;
    float sq = S * S;
    sq += __shfl_xor(sq, 1, 64);
    sq += __shfl_xor(sq, 2, 64);
    sq += __shfl_xor(sq, 4, 64);
    sq += __shfl_xor(sq, 8, 64);
    const float n = sqrtf(sq);
    float v = S * (n / (1.f + sq));
    if (SM == 1) v += v0T[g];
    if (SM == 2) dst[((size_t)b * J_ + j) * M_ + m] = v;   // standard [b][j][m]
    else         dst[g] = v;                                // vT layout
}

extern "C" void kernel_launch(void* const* d_in, const int* in_sizes, int n_in,
                              void* d_out, int out_size, void* d_ws, size_t ws_size,
                              hipStream_t stream) {
    const float* x  = (const float*)d_in[0];   // [128][1152][8]
    const float* Ws = (const float*)d_in[1];   // [10][1152][16][8]
    float* out = (float*)d_out;                // [128][10][16]

    float* xT    = (float*)d_ws;                           // 1,179,648
    float* sp    = xT + (size_t)RW * B_;                   // 2,621,440
    float* v0T   = sp + (size_t)NKT * J_ * B_ * M_;        //    20,480
    float* vsumT = v0T + J_ * B_ * M_;                     //    20,480

    xpose_kernel<<<dim3(RW / 64, 2), 256, 0, stream>>>(x, xT);

    iter_kernel<0><<<dim3(NKT, 2), 640, 0, stream>>>(xT, Ws, nullptr, sp);
    squash_kernel<0><<<80, 256, 0, stream>>>(sp, nullptr, v0T);

    iter_kernel<1><<<dim3(NKT, 2), 640, 0, stream>>>(xT, Ws, v0T, sp);
    squash_kernel<1><<<80, 256, 0, stream>>>(sp, v0T, vsumT);

    iter_kernel<1><<<dim3(NKT, 2), 640, 0, stream>>>(xT, Ws, vsumT, sp);
    squash_kernel<2><<<80, 256, 0, stream>>>(sp, nullptr, out);
}